// Round 2
// baseline (552.544 us; speedup 1.0000x reference)
//
#include <hip/hip_runtime.h>
#include <hip/hip_bf16.h>
#include <cstdint>
#include <cstddef>

// LinOSS block: B=32, T=4096, H=256, S=256, M = B*T = 131072
// v5: kernel-count 6 -> 4.
//  - gemm_ln: LayerNorm fused into GEMM1 staging (reads x f32 directly,
//    writes xn + u + per-chunk carries). Removes ln_kernel + 67MB.
//  - gemm_fused: GEMM2 (W2, + direct*xn + gelu) and GEMM3 (W3, + x + bias)
//    fused; gelu'd "mixed" lives only in LDS (Xs2). Removes 134MB + a launch.
//    W2 resident in VGPRs; W3 streamed from L2 per tile (3-slot rolling buf).
//  - scan_prefix: 8-wide batched loads to pipeline the serial chain.

typedef __bf16 bf16x8 __attribute__((ext_vector_type(8)));
typedef __bf16 bf16x4 __attribute__((ext_vector_type(4)));
typedef float  f32x4  __attribute__((ext_vector_type(4)));
typedef unsigned int u32x4 __attribute__((ext_vector_type(4)));

#define BB 32
#define TT 4096
#define HH 256
#define SS 256
#define MTOT (BB*TT)          // 131072
#define NCHUNK 64             // chunks of 64 timesteps
#define NT 8                  // 32-row tiles per block -> 256 rows/block

// ---------------- prep: weight cast + coeff ----------------
__global__ void prep_kernel(const float* __restrict__ w1, const float* __restrict__ w2,
                            const float* __restrict__ w3,
                            __bf16* __restrict__ w1b, __bf16* __restrict__ w2b,
                            __bf16* __restrict__ w3b,
                            const float* __restrict__ a_diag, const float* __restrict__ g_diag,
                            const float* __restrict__ dt,
                            float* __restrict__ coeff, float* __restrict__ cL) {
    int i = blockIdx.x * 256 + threadIdx.x;
    w1b[i] = (__bf16)w1[i];
    w2b[i] = (__bf16)w2[i];
    w3b[i] = (__bf16)w3[i];
    if (i < SS) {
        float d = dt[i];
        float sp = (d > 20.f) ? d : log1pf(expf(d));      // softplus
        float dts = sp + 1e-4f;
        float omega = a_diag[i] * dts;
        float gg = g_diag[i];
        float spg = (gg > 20.f) ? gg : log1pf(expf(gg));
        float dec = expf(-spg * dts);
        float c = dec * dec * cosf(omega);
        coeff[i] = c;
        float p = c;
        #pragma unroll
        for (int q = 0; q < 6; ++q) p = p * p;            // c^64
        cL[i] = p;
    }
}

// in-LDS scan of one 32x256 bf16 tile (u -> states), column s = tid, 16B-granule
// swizzle g^(m&15). Serial over rows, batched 8 (independent reads, dep fma chain).
__device__ __forceinline__ void scan_xs_tile(__bf16* Xs, int tid, float c, float& st) {
    const int gb = tid >> 3, bo = (tid & 7) << 1;
    #pragma unroll
    for (int g4 = 0; g4 < 4; ++g4) {
        float v[8];
        #pragma unroll
        for (int r = 0; r < 8; ++r) {
            const int m = g4 * 8 + r;
            v[r] = (float)*(const __bf16*)((const char*)Xs + m * 512 + (((gb ^ (m & 15)) << 4) | bo));
        }
        __bf16 w[8];
        #pragma unroll
        for (int r = 0; r < 8; ++r) { st = c * st + v[r]; w[r] = (__bf16)st; }
        #pragma unroll
        for (int r = 0; r < 8; ++r) {
            const int m = g4 * 8 + r;
            *(__bf16*)((char*)Xs + m * 512 + (((gb ^ (m & 15)) << 4) | bo)) = w[r];
        }
    }
}

// read-only carry scan of one 32x256 Es tile (8B-granule swizzle gn^((m&15)<<2))
__device__ __forceinline__ void scan_es_carry(const __bf16* Es, int tid, float c, float& st) {
    const int gb = tid >> 2, bo = (tid & 3) << 1;
    #pragma unroll
    for (int g4 = 0; g4 < 4; ++g4) {
        float v[8];
        #pragma unroll
        for (int r = 0; r < 8; ++r) {
            const int m = g4 * 8 + r;
            v[r] = (float)*(const __bf16*)((const char*)Es + m * 512 + (((gb ^ ((m & 15) << 2)) << 3) | bo));
        }
        #pragma unroll
        for (int r = 0; r < 8; ++r) st = c * st + v[r];
    }
}

// ---------------- GEMM1 + LayerNorm + carries ----------------
// u[m,s] = sum_h W1[s,h] xn[m,h], xn = LN(x). Block: 512 thr, 8 waves x 32n.
// Staging reads x f32 (1 row per wave), LNs in-wave, writes bf16 LDS + xn global.
__global__ __launch_bounds__(512, 4) void gemm_ln_kernel(
    const __bf16* __restrict__ W,    // w1b [256][256]
    const float* __restrict__ x,     // [M][256] f32
    const float* __restrict__ nw, const float* __restrict__ nb,
    __bf16* __restrict__ xn, __bf16* __restrict__ u,
    const float* __restrict__ coeff, const float* __restrict__ state0,
    float* __restrict__ carry)
{
    __shared__ __bf16 Xs[32 * 256];   // 16 KB, 16B-granule swizzle g^(m&15)
    __shared__ __bf16 Es[32 * 256];   // 16 KB, 8B-granule swizzle gn^((m&15)<<2)

    const int tid  = threadIdx.x;
    const int lane = tid & 63;
    const int wid  = tid >> 6;          // 0..7
    const int l15  = lane & 15, quad = lane >> 4;

    bf16x8 Wf[2][8];
    #pragma unroll
    for (int jn = 0; jn < 2; ++jn) {
        const int n = wid * 32 + jn * 16 + l15;
        #pragma unroll
        for (int kb = 0; kb < 8; ++kb)
            Wf[jn][kb] = *(const bf16x8*)&W[(size_t)n * 256 + kb * 32 + quad * 8];
    }

    const int bxi = blockIdx.x;
    const int bb  = bxi >> 4;           // batch
    const int chb = (bxi & 15) * 4;     // first chunk of this block
    float c_s = 0.f, s0v = 0.f;
    if (tid < 256) {
        c_s = coeff[tid];
        if (chb == 0) s0v = state0[(size_t)bb * 256 + tid];
    }

    const f32x4 wn4 = *(const f32x4*)&nw[lane * 4];
    const f32x4 bn4 = *(const f32x4*)&nb[lane * 4];

    const size_t mbase = (size_t)bxi * 256;

    f32x4 pf[4];   // 4 rows per wave (row = j*8 + wid), full row per wave
    auto ln_load = [&](int tile) {
        #pragma unroll
        for (int j = 0; j < 4; ++j) {
            const int m = j * 8 + wid;
            pf[j] = *(const f32x4*)&x[(mbase + (size_t)tile * 32 + m) * 256 + lane * 4];
        }
    };
    auto ln_store = [&](int tile) {
        #pragma unroll
        for (int j = 0; j < 4; ++j) {
            const int m = j * 8 + wid;
            f32x4 v = pf[j];
            float s  = v[0] + v[1] + v[2] + v[3];
            float ss = v[0]*v[0] + v[1]*v[1] + v[2]*v[2] + v[3]*v[3];
            #pragma unroll
            for (int off = 32; off; off >>= 1) {
                s  += __shfl_xor(s,  off, 64);
                ss += __shfl_xor(ss, off, 64);
            }
            float mu  = s * (1.f/256.f);
            float var = ss * (1.f/256.f) - mu * mu;
            float sc  = rsqrtf(var + 1e-5f);
            bf16x4 pk;
            #pragma unroll
            for (int q2 = 0; q2 < 4; ++q2)
                pk[q2] = (__bf16)((v[q2] - mu) * sc * wn4[q2] + bn4[q2]);
            // LDS (16B granule = lane>>1, half = lane&1)
            *(bf16x4*)((char*)Xs + m * 512 + ((((lane >> 1) ^ (m & 15)) << 4) | ((lane & 1) << 3))) = pk;
            // global xn (coalesced 8B/lane)
            *(bf16x4*)&xn[(mbase + (size_t)tile * 32 + m) * 256 + lane * 4] = pk;
        }
    };

    ln_load(0);
    ln_store(0);
    __syncthreads();
    ln_load(1);

    const int hrow = tid >> 5;   // 0..15
    const int nc   = tid & 31;
    float stc = 0.f;

    for (int it = 0; it < NT; ++it) {
        const size_t mt0 = mbase + (size_t)it * 32;

        f32x4 acc[2][2] = {};
        #pragma unroll
        for (int kb = 0; kb < 8; ++kb) {
            bf16x8 xf[2];
            #pragma unroll
            for (int im = 0; im < 2; ++im)
                xf[im] = *(const bf16x8*)((const char*)Xs + (l15 + im * 16) * 512
                                          + (((kb * 4 + quad) ^ l15) * 16));
            #pragma unroll
            for (int jn = 0; jn < 2; ++jn)
                #pragma unroll
                for (int im = 0; im < 2; ++im)
                    acc[im][jn] = __builtin_amdgcn_mfma_f32_16x16x32_bf16(
                        Wf[jn][kb], xf[im], acc[im][jn], 0, 0, 0);
        }
        __syncthreads();   // A: Xs reads done

        if (it + 1 < NT) ln_store(it + 1);
        #pragma unroll
        for (int im = 0; im < 2; ++im) {
            const int m = l15 + im * 16;
            #pragma unroll
            for (int jn = 0; jn < 2; ++jn) {
                const int gn = wid * 8 + jn * 4 + quad;
                bf16x4 pk;
                #pragma unroll
                for (int r = 0; r < 4; ++r) pk[r] = (__bf16)acc[im][jn][r];
                *(bf16x4*)((char*)Es + m * 512 + ((gn ^ (l15 << 2)) * 8)) = pk;
            }
        }
        __syncthreads();   // E

        if (it + 2 < NT) ln_load(it + 2);

        #pragma unroll
        for (int r = 0; r < 2; ++r) {
            const int m = r * 16 + hrow;
            bf16x8 ev = *(const bf16x8*)((const char*)Es + m * 512 + (((nc * 2) ^ (hrow << 2)) * 8));
            *(bf16x8*)&u[(mt0 + m) * 256 + nc * 8] = ev;
        }

        if (tid < 256) {
            if ((it & 1) == 0) stc = (it == 0 && chb == 0) ? s0v : 0.f;
            scan_es_carry(Es, tid, c_s, stc);
            if ((it & 1) == 1)
                carry[((size_t)bb * 64 + (chb + (it >> 1))) * 256 + tid] = stc;
        }
    }
}

// ---------------- fused GEMM2 + gelu + GEMM3 ----------------
// states = scan(u); mixed = gelu(W2@states + direct*xn); y = x + W3@mixed + b.
// mixed lives only in Xs2 (LDS). W2 resident; W3 streamed from L2 per tile.
__global__ __launch_bounds__(512, 4) void gemm_fused_kernel(
    const __bf16* __restrict__ W2, const __bf16* __restrict__ W3,
    const __bf16* __restrict__ u, const __bf16* __restrict__ xn,
    const float* __restrict__ dvec,
    const float* __restrict__ xres, const float* __restrict__ bias,
    const float* __restrict__ coeff, const float* __restrict__ state0,
    const float* __restrict__ carry,
    float* __restrict__ y)
{
    __shared__ __bf16 Xs [32 * 256];  // u -> states staging
    __shared__ __bf16 Es [32 * 256];  // epilogue transpose buffer (both GEMMs)
    __shared__ __bf16 Xs2[32 * 256];  // gelu'd mixed (B-operand of GEMM3)

    const int tid  = threadIdx.x;
    const int lane = tid & 63;
    const int wid  = tid >> 6;
    const int l15  = lane & 15, quad = lane >> 4;

    bf16x8 W2f[2][8];
    #pragma unroll
    for (int jn = 0; jn < 2; ++jn) {
        const int n = wid * 32 + jn * 16 + l15;
        #pragma unroll
        for (int kb = 0; kb < 8; ++kb)
            W2f[jn][kb] = *(const bf16x8*)&W2[(size_t)n * 256 + kb * 32 + quad * 8];
    }
    const __bf16* w3p0 = W3 + (size_t)(wid * 32 + l15) * 256 + quad * 8;
    const __bf16* w3p1 = w3p0 + 16 * 256;

    const int bxi = blockIdx.x;
    const int bb  = bxi >> 4;
    const int chb = (bxi & 15) * 4;
    float c_s = 0.f, cin0 = 0.f, cin1 = 0.f, cin2 = 0.f, cin3 = 0.f;
    if (tid < 256) {
        c_s  = coeff[tid];
        cin0 = (chb == 0) ? state0[(size_t)bb * 256 + tid]
                          : carry[((size_t)bb * 64 + chb - 1) * 256 + tid];
        cin1 = carry[((size_t)bb * 64 + chb + 0) * 256 + tid];
        cin2 = carry[((size_t)bb * 64 + chb + 1) * 256 + tid];
        cin3 = carry[((size_t)bb * 64 + chb + 2) * 256 + tid];
    }

    int sdst[2], srow[2];
    const int g = tid & 31;
    #pragma unroll
    for (int j = 0; j < 2; ++j) {
        const int m = j * 16 + (tid >> 5);
        srow[j] = m;
        sdst[j] = m * 512 + ((g ^ (m & 15)) * 16);
    }
    const int colb = g * 16;
    const size_t mbase = (size_t)bxi * 256;
    const char* Ub = (const char*)u;

    u32x4 pf[2];
    #pragma unroll
    for (int j = 0; j < 2; ++j)
        pf[j] = *(const u32x4*)(Ub + (mbase + srow[j]) * 512 + colb);
    #pragma unroll
    for (int j = 0; j < 2; ++j)
        *(u32x4*)((char*)Xs + sdst[j]) = pf[j];
    __syncthreads();
    #pragma unroll
    for (int j = 0; j < 2; ++j)
        pf[j] = *(const u32x4*)(Ub + (mbase + 32 + srow[j]) * 512 + colb);

    float st = 0.f;
    if (tid < 256) { st = cin0; scan_xs_tile(Xs, tid, c_s, st); }
    __syncthreads();

    const int hrow = tid >> 5;
    const int nc   = tid & 31;

    for (int it = 0; it < NT; ++it) {
        const size_t mt0 = mbase + (size_t)it * 32;

        // ---- GEMM2 on states(it) ----
        f32x4 acc[2][2] = {};
        #pragma unroll
        for (int kb = 0; kb < 8; ++kb) {
            bf16x8 xf[2];
            #pragma unroll
            for (int im = 0; im < 2; ++im)
                xf[im] = *(const bf16x8*)((const char*)Xs + (l15 + im * 16) * 512
                                          + (((kb * 4 + quad) ^ l15) * 16));
            #pragma unroll
            for (int jn = 0; jn < 2; ++jn)
                #pragma unroll
                for (int im = 0; im < 2; ++im)
                    acc[im][jn] = __builtin_amdgcn_mfma_f32_16x16x32_bf16(
                        W2f[jn][kb], xf[im], acc[im][jn], 0, 0, 0);
        }
        __syncthreads();   // A

        if (it + 1 < NT) {
            #pragma unroll
            for (int j = 0; j < 2; ++j)
                *(u32x4*)((char*)Xs + sdst[j]) = pf[j];
        }
        #pragma unroll
        for (int im = 0; im < 2; ++im) {
            const int m = l15 + im * 16;
            #pragma unroll
            for (int jn = 0; jn < 2; ++jn) {
                const int gn = wid * 8 + jn * 4 + quad;
                bf16x4 pk;
                #pragma unroll
                for (int r = 0; r < 4; ++r) pk[r] = (__bf16)acc[im][jn][r];
                *(bf16x4*)((char*)Es + m * 512 + ((gn ^ (l15 << 2)) * 8)) = pk;
            }
        }
        __syncthreads();   // E

        if (it + 2 < NT) {
            #pragma unroll
            for (int j = 0; j < 2; ++j)
                pf[j] = *(const u32x4*)(Ub + (mt0 + 64 + srow[j]) * 512 + colb);
        }
        if (it + 1 < NT && tid < 256) {
            const int itt = it + 1;
            if ((itt & 1) == 0) {
                const int k = itt >> 1;
                st = (k == 1) ? cin1 : (k == 2) ? cin2 : cin3;
            }
            scan_xs_tile(Xs, tid, c_s, st);
        }

        // ---- store-phase 1: mixed = acc + direct*xn -> gelu -> Xs2 ----
        #pragma unroll
        for (int r = 0; r < 2; ++r) {
            const int m = r * 16 + hrow;
            bf16x8 ev = *(const bf16x8*)((const char*)Es + m * 512 + (((nc * 2) ^ (hrow << 2)) * 8));
            const size_t gidx = (mt0 + m) * 256 + nc * 8;
            bf16x8 xv = *(const bf16x8*)&xn[gidx];
            f32x4 d0 = *(const f32x4*)&dvec[nc * 8];
            f32x4 d1 = *(const f32x4*)&dvec[nc * 8 + 4];
            bf16x8 pk;
            #pragma unroll
            for (int jj = 0; jj < 8; ++jj) {
                float dj = (jj < 4) ? d0[jj] : d1[jj - 4];
                float t = (float)ev[jj] + dj * (float)xv[jj];
                float q = t + 0.044715f * t * t * t;
                float e = __expf(-1.5957691216057308f * q);
                pk[jj] = (__bf16)(t * __builtin_amdgcn_rcpf(1.f + e));
            }
            *(bf16x8*)((char*)Xs2 + m * 512 + ((nc ^ (m & 15)) * 16)) = pk;
        }
        __syncthreads();   // F: Xs2 ready; scanned Xs(it+1) visible

        // ---- GEMM3 on Xs2, W3 streamed (3-slot rolling, static idx by unroll) ----
        f32x4 acc2[2][2] = {};
        bf16x8 wr[3][2];
        wr[0][0] = *(const bf16x8*)(w3p0);
        wr[0][1] = *(const bf16x8*)(w3p1);
        wr[1][0] = *(const bf16x8*)(w3p0 + 32);
        wr[1][1] = *(const bf16x8*)(w3p1 + 32);
        #pragma unroll
        for (int kb = 0; kb < 8; ++kb) {
            if (kb + 2 < 8) {
                wr[(kb + 2) % 3][0] = *(const bf16x8*)(w3p0 + (kb + 2) * 32);
                wr[(kb + 2) % 3][1] = *(const bf16x8*)(w3p1 + (kb + 2) * 32);
            }
            bf16x8 xf[2];
            #pragma unroll
            for (int im = 0; im < 2; ++im)
                xf[im] = *(const bf16x8*)((const char*)Xs2 + (l15 + im * 16) * 512
                                          + (((kb * 4 + quad) ^ l15) * 16));
            #pragma unroll
            for (int jn = 0; jn < 2; ++jn)
                #pragma unroll
                for (int im = 0; im < 2; ++im)
                    acc2[im][jn] = __builtin_amdgcn_mfma_f32_16x16x32_bf16(
                        wr[kb % 3][jn], xf[im], acc2[im][jn], 0, 0, 0);
        }
        __syncthreads();   // A2

        #pragma unroll
        for (int im = 0; im < 2; ++im) {
            const int m = l15 + im * 16;
            #pragma unroll
            for (int jn = 0; jn < 2; ++jn) {
                const int gn = wid * 8 + jn * 4 + quad;
                bf16x4 pk;
                #pragma unroll
                for (int r = 0; r < 4; ++r) pk[r] = (__bf16)acc2[im][jn][r];
                *(bf16x4*)((char*)Es + m * 512 + ((gn ^ (l15 << 2)) * 8)) = pk;
            }
        }
        __syncthreads();   // E2

        // ---- store-phase 2: y = x + proj + b (f32) ----
        #pragma unroll
        for (int r = 0; r < 2; ++r) {
            const int m = r * 16 + hrow;
            bf16x8 ev = *(const bf16x8*)((const char*)Es + m * 512 + (((nc * 2) ^ (hrow << 2)) * 8));
            const size_t gidx = (mt0 + m) * 256 + nc * 8;
            f32x4 x0 = *(const f32x4*)&xres[gidx];
            f32x4 x1 = *(const f32x4*)&xres[gidx + 4];
            f32x4 b0 = *(const f32x4*)&bias[nc * 8];
            f32x4 b1 = *(const f32x4*)&bias[nc * 8 + 4];
            f32x4 y0, y1;
            #pragma unroll
            for (int jj = 0; jj < 4; ++jj) {
                y0[jj] = x0[jj] + (float)ev[jj]     + b0[jj];
                y1[jj] = x1[jj] + (float)ev[jj + 4] + b1[jj];
            }
            *(f32x4*)&y[gidx]     = y0;
            *(f32x4*)&y[gidx + 4] = y1;
        }
    }
}

// ---------------- scan pass 2: prefix over chunk carries ----------------
__global__ __launch_bounds__(256) void scan_prefix(float* carry, const float* __restrict__ cL,
                            float* __restrict__ fs_out) {
    int b = blockIdx.x, s = threadIdx.x;
    float cl = cL[s];
    float P = 0.f;
    #pragma unroll
    for (int jo = 0; jo < 8; ++jo) {
        float v[8];
        #pragma unroll
        for (int r = 0; r < 8; ++r)
            v[r] = carry[((size_t)b * NCHUNK + jo * 8 + r) * SS + s];
        float w[8];
        #pragma unroll
        for (int r = 0; r < 8; ++r) { P = cl * P + v[r]; w[r] = P; }
        #pragma unroll
        for (int r = 0; r < 8; ++r)
            carry[((size_t)b * NCHUNK + jo * 8 + r) * SS + s] = w[r];
    }
    fs_out[b * SS + s] = P;
}

extern "C" void kernel_launch(void* const* d_in, const int* in_sizes, int n_in,
                              void* d_out, int out_size, void* d_ws, size_t ws_size,
                              hipStream_t stream) {
    const float* x      = (const float*)d_in[0];
    const float* state0 = (const float*)d_in[1];
    const float* w1     = (const float*)d_in[2];   // in_to_state [S,H]
    const float* w2     = (const float*)d_in[3];   // state_to_hidden [H,S]
    const float* direct = (const float*)d_in[4];
    const float* a_diag = (const float*)d_in[5];
    const float* g_diag = (const float*)d_in[6];
    const float* dt     = (const float*)d_in[7];
    const float* norm_w = (const float*)d_in[8];
    const float* norm_b = (const float*)d_in[9];
    const float* w3     = (const float*)d_in[10];  // out_w [H,H]
    const float* out_b  = (const float*)d_in[11];

    char* ws = (char*)d_ws;
    const size_t MH2 = (size_t)MTOT * HH * 2;      // 67108864
    __bf16* xn    = (__bf16*)(ws);                  // [M,H] bf16
    __bf16* u     = (__bf16*)(ws + MH2);            // [M,S] bf16
    __bf16* w1b   = (__bf16*)(ws + 2*MH2);
    __bf16* w2b   = (__bf16*)(ws + 2*MH2 + 131072);
    __bf16* w3b   = (__bf16*)(ws + 2*MH2 + 262144);
    float*  coeff = (float*)(ws + 2*MH2 + 393216);
    float*  cL    = (float*)(ws + 2*MH2 + 394240);
    float*  carry = (float*)(ws + 2*MH2 + 395264);  // [B, NCHUNK, S] f32 = 2MB

    float* y_out  = (float*)d_out;
    float* fs_out = (float*)d_out + (size_t)MTOT * HH;

    prep_kernel<<<256, 256, 0, stream>>>(w1, w2, w3, w1b, w2b, w3b,
                                         a_diag, g_diag, dt, coeff, cL);
    gemm_ln_kernel<<<512, 512, 0, stream>>>(w1b, x, norm_w, norm_b, xn, u,
                                            coeff, state0, carry);
    scan_prefix<<<BB, 256, 0, stream>>>(carry, cL, fs_out);
    gemm_fused_kernel<<<512, 512, 0, stream>>>(w2b, w3b, u, xn, direct, x, out_b,
                                               coeff, state0, carry, y_out);
}

// Round 3
// 372.956 us; speedup vs baseline: 1.4815x; 1.4815x over previous
//
#include <hip/hip_runtime.h>
#include <hip/hip_bf16.h>
#include <cstdint>
#include <cstddef>

// LinOSS block: B=32, T=4096, H=256, S=256, M = B*T = 131072
// v6 = v5 with the register-starvation fix.
// ROUND-2 FINDING: __launch_bounds__(512, 4) capped VGPRs at 64 (second arg
// acted as min-BLOCKS/CU: 4 blk x 8 waves = 8 waves/SIMD -> 512/8 = 64 regs).
// W fragments + accumulators (~150 VGPR) were spilled to scratch: gemm_fused
// showed +306MB FETCH / +159MB WRITE of pure spill traffic, MfmaUtil 5%.
// Fix: __launch_bounds__(512, 1) -> 2 waves/EU -> 256-VGPR budget, no spill.
// (1 block/CU; fillBuffer reaches 85% BW at 9% occupancy, so issue-rate not
// occupancy is the constraint once scratch traffic is gone.)

typedef __bf16 bf16x8 __attribute__((ext_vector_type(8)));
typedef __bf16 bf16x4 __attribute__((ext_vector_type(4)));
typedef float  f32x4  __attribute__((ext_vector_type(4)));
typedef unsigned int u32x4 __attribute__((ext_vector_type(4)));

#define BB 32
#define TT 4096
#define HH 256
#define SS 256
#define MTOT (BB*TT)          // 131072
#define NCHUNK 64             // chunks of 64 timesteps
#define NT 8                  // 32-row tiles per block -> 256 rows/block

// ---------------- prep: weight cast + coeff ----------------
__global__ void prep_kernel(const float* __restrict__ w1, const float* __restrict__ w2,
                            const float* __restrict__ w3,
                            __bf16* __restrict__ w1b, __bf16* __restrict__ w2b,
                            __bf16* __restrict__ w3b,
                            const float* __restrict__ a_diag, const float* __restrict__ g_diag,
                            const float* __restrict__ dt,
                            float* __restrict__ coeff, float* __restrict__ cL) {
    int i = blockIdx.x * 256 + threadIdx.x;
    w1b[i] = (__bf16)w1[i];
    w2b[i] = (__bf16)w2[i];
    w3b[i] = (__bf16)w3[i];
    if (i < SS) {
        float d = dt[i];
        float sp = (d > 20.f) ? d : log1pf(expf(d));      // softplus
        float dts = sp + 1e-4f;
        float omega = a_diag[i] * dts;
        float gg = g_diag[i];
        float spg = (gg > 20.f) ? gg : log1pf(expf(gg));
        float dec = expf(-spg * dts);
        float c = dec * dec * cosf(omega);
        coeff[i] = c;
        float p = c;
        #pragma unroll
        for (int q = 0; q < 6; ++q) p = p * p;            // c^64
        cL[i] = p;
    }
}

// in-LDS scan of one 32x256 bf16 tile (u -> states), column s = tid, 16B-granule
// swizzle g^(m&15). Serial over rows, batched 8 (independent reads, dep fma chain).
__device__ __forceinline__ void scan_xs_tile(__bf16* Xs, int tid, float c, float& st) {
    const int gb = tid >> 3, bo = (tid & 7) << 1;
    #pragma unroll
    for (int g4 = 0; g4 < 4; ++g4) {
        float v[8];
        #pragma unroll
        for (int r = 0; r < 8; ++r) {
            const int m = g4 * 8 + r;
            v[r] = (float)*(const __bf16*)((const char*)Xs + m * 512 + (((gb ^ (m & 15)) << 4) | bo));
        }
        __bf16 w[8];
        #pragma unroll
        for (int r = 0; r < 8; ++r) { st = c * st + v[r]; w[r] = (__bf16)st; }
        #pragma unroll
        for (int r = 0; r < 8; ++r) {
            const int m = g4 * 8 + r;
            *(__bf16*)((char*)Xs + m * 512 + (((gb ^ (m & 15)) << 4) | bo)) = w[r];
        }
    }
}

// read-only carry scan of one 32x256 Es tile (8B-granule swizzle gn^((m&15)<<2))
__device__ __forceinline__ void scan_es_carry(const __bf16* Es, int tid, float c, float& st) {
    const int gb = tid >> 2, bo = (tid & 3) << 1;
    #pragma unroll
    for (int g4 = 0; g4 < 4; ++g4) {
        float v[8];
        #pragma unroll
        for (int r = 0; r < 8; ++r) {
            const int m = g4 * 8 + r;
            v[r] = (float)*(const __bf16*)((const char*)Es + m * 512 + (((gb ^ ((m & 15) << 2)) << 3) | bo));
        }
        #pragma unroll
        for (int r = 0; r < 8; ++r) st = c * st + v[r];
    }
}

// ---------------- GEMM1 + LayerNorm + carries ----------------
__global__ __launch_bounds__(512, 1) void gemm_ln_kernel(
    const __bf16* __restrict__ W,    // w1b [256][256]
    const float* __restrict__ x,     // [M][256] f32
    const float* __restrict__ nw, const float* __restrict__ nb,
    __bf16* __restrict__ xn, __bf16* __restrict__ u,
    const float* __restrict__ coeff, const float* __restrict__ state0,
    float* __restrict__ carry)
{
    __shared__ __bf16 Xs[32 * 256];   // 16 KB, 16B-granule swizzle g^(m&15)
    __shared__ __bf16 Es[32 * 256];   // 16 KB, 8B-granule swizzle gn^((m&15)<<2)

    const int tid  = threadIdx.x;
    const int lane = tid & 63;
    const int wid  = tid >> 6;          // 0..7
    const int l15  = lane & 15, quad = lane >> 4;

    bf16x8 Wf[2][8];
    #pragma unroll
    for (int jn = 0; jn < 2; ++jn) {
        const int n = wid * 32 + jn * 16 + l15;
        #pragma unroll
        for (int kb = 0; kb < 8; ++kb)
            Wf[jn][kb] = *(const bf16x8*)&W[(size_t)n * 256 + kb * 32 + quad * 8];
    }

    const int bxi = blockIdx.x;
    const int bb  = bxi >> 4;           // batch
    const int chb = (bxi & 15) * 4;     // first chunk of this block
    float c_s = 0.f, s0v = 0.f;
    if (tid < 256) {
        c_s = coeff[tid];
        if (chb == 0) s0v = state0[(size_t)bb * 256 + tid];
    }

    const f32x4 wn4 = *(const f32x4*)&nw[lane * 4];
    const f32x4 bn4 = *(const f32x4*)&nb[lane * 4];

    const size_t mbase = (size_t)bxi * 256;

    f32x4 pf[4];   // 4 rows per wave (row = j*8 + wid), full row per wave
    auto ln_load = [&](int tile) {
        #pragma unroll
        for (int j = 0; j < 4; ++j) {
            const int m = j * 8 + wid;
            pf[j] = *(const f32x4*)&x[(mbase + (size_t)tile * 32 + m) * 256 + lane * 4];
        }
    };
    auto ln_store = [&](int tile) {
        #pragma unroll
        for (int j = 0; j < 4; ++j) {
            const int m = j * 8 + wid;
            f32x4 v = pf[j];
            float s  = v[0] + v[1] + v[2] + v[3];
            float ss = v[0]*v[0] + v[1]*v[1] + v[2]*v[2] + v[3]*v[3];
            #pragma unroll
            for (int off = 32; off; off >>= 1) {
                s  += __shfl_xor(s,  off, 64);
                ss += __shfl_xor(ss, off, 64);
            }
            float mu  = s * (1.f/256.f);
            float var = ss * (1.f/256.f) - mu * mu;
            float sc  = rsqrtf(var + 1e-5f);
            bf16x4 pk;
            #pragma unroll
            for (int q2 = 0; q2 < 4; ++q2)
                pk[q2] = (__bf16)((v[q2] - mu) * sc * wn4[q2] + bn4[q2]);
            *(bf16x4*)((char*)Xs + m * 512 + ((((lane >> 1) ^ (m & 15)) << 4) | ((lane & 1) << 3))) = pk;
            *(bf16x4*)&xn[(mbase + (size_t)tile * 32 + m) * 256 + lane * 4] = pk;
        }
    };

    ln_load(0);
    ln_store(0);
    __syncthreads();
    ln_load(1);

    const int hrow = tid >> 5;   // 0..15
    const int nc   = tid & 31;
    float stc = 0.f;

    for (int it = 0; it < NT; ++it) {
        const size_t mt0 = mbase + (size_t)it * 32;

        f32x4 acc[2][2] = {};
        #pragma unroll
        for (int kb = 0; kb < 8; ++kb) {
            bf16x8 xf[2];
            #pragma unroll
            for (int im = 0; im < 2; ++im)
                xf[im] = *(const bf16x8*)((const char*)Xs + (l15 + im * 16) * 512
                                          + (((kb * 4 + quad) ^ l15) * 16));
            #pragma unroll
            for (int jn = 0; jn < 2; ++jn)
                #pragma unroll
                for (int im = 0; im < 2; ++im)
                    acc[im][jn] = __builtin_amdgcn_mfma_f32_16x16x32_bf16(
                        Wf[jn][kb], xf[im], acc[im][jn], 0, 0, 0);
        }
        __syncthreads();   // A: Xs reads done

        if (it + 1 < NT) ln_store(it + 1);
        #pragma unroll
        for (int im = 0; im < 2; ++im) {
            const int m = l15 + im * 16;
            #pragma unroll
            for (int jn = 0; jn < 2; ++jn) {
                const int gn = wid * 8 + jn * 4 + quad;
                bf16x4 pk;
                #pragma unroll
                for (int r = 0; r < 4; ++r) pk[r] = (__bf16)acc[im][jn][r];
                *(bf16x4*)((char*)Es + m * 512 + ((gn ^ (l15 << 2)) * 8)) = pk;
            }
        }
        __syncthreads();   // E

        if (it + 2 < NT) ln_load(it + 2);

        #pragma unroll
        for (int r = 0; r < 2; ++r) {
            const int m = r * 16 + hrow;
            bf16x8 ev = *(const bf16x8*)((const char*)Es + m * 512 + (((nc * 2) ^ (hrow << 2)) * 8));
            *(bf16x8*)&u[(mt0 + m) * 256 + nc * 8] = ev;
        }

        if (tid < 256) {
            if ((it & 1) == 0) stc = (it == 0 && chb == 0) ? s0v : 0.f;
            scan_es_carry(Es, tid, c_s, stc);
            if ((it & 1) == 1)
                carry[((size_t)bb * 64 + (chb + (it >> 1))) * 256 + tid] = stc;
        }
    }
}

// ---------------- fused GEMM2 + gelu + GEMM3 ----------------
__global__ __launch_bounds__(512, 1) void gemm_fused_kernel(
    const __bf16* __restrict__ W2, const __bf16* __restrict__ W3,
    const __bf16* __restrict__ u, const __bf16* __restrict__ xn,
    const float* __restrict__ dvec,
    const float* __restrict__ xres, const float* __restrict__ bias,
    const float* __restrict__ coeff, const float* __restrict__ state0,
    const float* __restrict__ carry,
    float* __restrict__ y)
{
    __shared__ __bf16 Xs [32 * 256];  // u -> states staging
    __shared__ __bf16 Es [32 * 256];  // epilogue transpose buffer (both GEMMs)
    __shared__ __bf16 Xs2[32 * 256];  // gelu'd mixed (B-operand of GEMM3)

    const int tid  = threadIdx.x;
    const int lane = tid & 63;
    const int wid  = tid >> 6;
    const int l15  = lane & 15, quad = lane >> 4;

    bf16x8 W2f[2][8];
    #pragma unroll
    for (int jn = 0; jn < 2; ++jn) {
        const int n = wid * 32 + jn * 16 + l15;
        #pragma unroll
        for (int kb = 0; kb < 8; ++kb)
            W2f[jn][kb] = *(const bf16x8*)&W2[(size_t)n * 256 + kb * 32 + quad * 8];
    }
    const __bf16* w3p0 = W3 + (size_t)(wid * 32 + l15) * 256 + quad * 8;
    const __bf16* w3p1 = w3p0 + 16 * 256;

    const int bxi = blockIdx.x;
    const int bb  = bxi >> 4;
    const int chb = (bxi & 15) * 4;
    float c_s = 0.f, cin0 = 0.f, cin1 = 0.f, cin2 = 0.f, cin3 = 0.f;
    if (tid < 256) {
        c_s  = coeff[tid];
        cin0 = (chb == 0) ? state0[(size_t)bb * 256 + tid]
                          : carry[((size_t)bb * 64 + chb - 1) * 256 + tid];
        cin1 = carry[((size_t)bb * 64 + chb + 0) * 256 + tid];
        cin2 = carry[((size_t)bb * 64 + chb + 1) * 256 + tid];
        cin3 = carry[((size_t)bb * 64 + chb + 2) * 256 + tid];
    }

    int sdst[2], srow[2];
    const int g = tid & 31;
    #pragma unroll
    for (int j = 0; j < 2; ++j) {
        const int m = j * 16 + (tid >> 5);
        srow[j] = m;
        sdst[j] = m * 512 + ((g ^ (m & 15)) * 16);
    }
    const int colb = g * 16;
    const size_t mbase = (size_t)bxi * 256;
    const char* Ub = (const char*)u;

    u32x4 pf[2];
    #pragma unroll
    for (int j = 0; j < 2; ++j)
        pf[j] = *(const u32x4*)(Ub + (mbase + srow[j]) * 512 + colb);
    #pragma unroll
    for (int j = 0; j < 2; ++j)
        *(u32x4*)((char*)Xs + sdst[j]) = pf[j];
    __syncthreads();
    #pragma unroll
    for (int j = 0; j < 2; ++j)
        pf[j] = *(const u32x4*)(Ub + (mbase + 32 + srow[j]) * 512 + colb);

    float st = 0.f;
    if (tid < 256) { st = cin0; scan_xs_tile(Xs, tid, c_s, st); }
    __syncthreads();

    const int hrow = tid >> 5;
    const int nc   = tid & 31;

    for (int it = 0; it < NT; ++it) {
        const size_t mt0 = mbase + (size_t)it * 32;

        // ---- GEMM2 on states(it) ----
        f32x4 acc[2][2] = {};
        #pragma unroll
        for (int kb = 0; kb < 8; ++kb) {
            bf16x8 xf[2];
            #pragma unroll
            for (int im = 0; im < 2; ++im)
                xf[im] = *(const bf16x8*)((const char*)Xs + (l15 + im * 16) * 512
                                          + (((kb * 4 + quad) ^ l15) * 16));
            #pragma unroll
            for (int jn = 0; jn < 2; ++jn)
                #pragma unroll
                for (int im = 0; im < 2; ++im)
                    acc[im][jn] = __builtin_amdgcn_mfma_f32_16x16x32_bf16(
                        W2f[jn][kb], xf[im], acc[im][jn], 0, 0, 0);
        }
        __syncthreads();   // A

        if (it + 1 < NT) {
            #pragma unroll
            for (int j = 0; j < 2; ++j)
                *(u32x4*)((char*)Xs + sdst[j]) = pf[j];
        }
        #pragma unroll
        for (int im = 0; im < 2; ++im) {
            const int m = l15 + im * 16;
            #pragma unroll
            for (int jn = 0; jn < 2; ++jn) {
                const int gn = wid * 8 + jn * 4 + quad;
                bf16x4 pk;
                #pragma unroll
                for (int r = 0; r < 4; ++r) pk[r] = (__bf16)acc[im][jn][r];
                *(bf16x4*)((char*)Es + m * 512 + ((gn ^ (l15 << 2)) * 8)) = pk;
            }
        }
        __syncthreads();   // E

        if (it + 2 < NT) {
            #pragma unroll
            for (int j = 0; j < 2; ++j)
                pf[j] = *(const u32x4*)(Ub + (mt0 + 64 + srow[j]) * 512 + colb);
        }
        if (it + 1 < NT && tid < 256) {
            const int itt = it + 1;
            if ((itt & 1) == 0) {
                const int k = itt >> 1;
                st = (k == 1) ? cin1 : (k == 2) ? cin2 : cin3;
            }
            scan_xs_tile(Xs, tid, c_s, st);
        }

        // ---- store-phase 1: mixed = acc + direct*xn -> gelu -> Xs2 ----
        #pragma unroll
        for (int r = 0; r < 2; ++r) {
            const int m = r * 16 + hrow;
            bf16x8 ev = *(const bf16x8*)((const char*)Es + m * 512 + (((nc * 2) ^ (hrow << 2)) * 8));
            const size_t gidx = (mt0 + m) * 256 + nc * 8;
            bf16x8 xv = *(const bf16x8*)&xn[gidx];
            f32x4 d0 = *(const f32x4*)&dvec[nc * 8];
            f32x4 d1 = *(const f32x4*)&dvec[nc * 8 + 4];
            bf16x8 pk;
            #pragma unroll
            for (int jj = 0; jj < 8; ++jj) {
                float dj = (jj < 4) ? d0[jj] : d1[jj - 4];
                float t = (float)ev[jj] + dj * (float)xv[jj];
                float q = t + 0.044715f * t * t * t;
                float e = __expf(-1.5957691216057308f * q);
                pk[jj] = (__bf16)(t * __builtin_amdgcn_rcpf(1.f + e));
            }
            *(bf16x8*)((char*)Xs2 + m * 512 + ((nc ^ (m & 15)) * 16)) = pk;
        }
        __syncthreads();   // F: Xs2 ready; scanned Xs(it+1) visible

        // ---- GEMM3 on Xs2, W3 streamed (3-slot rolling, static idx by unroll) ----
        f32x4 acc2[2][2] = {};
        bf16x8 wr[3][2];
        wr[0][0] = *(const bf16x8*)(w3p0);
        wr[0][1] = *(const bf16x8*)(w3p1);
        wr[1][0] = *(const bf16x8*)(w3p0 + 32);
        wr[1][1] = *(const bf16x8*)(w3p1 + 32);
        #pragma unroll
        for (int kb = 0; kb < 8; ++kb) {
            if (kb + 2 < 8) {
                wr[(kb + 2) % 3][0] = *(const bf16x8*)(w3p0 + (kb + 2) * 32);
                wr[(kb + 2) % 3][1] = *(const bf16x8*)(w3p1 + (kb + 2) * 32);
            }
            bf16x8 xf[2];
            #pragma unroll
            for (int im = 0; im < 2; ++im)
                xf[im] = *(const bf16x8*)((const char*)Xs2 + (l15 + im * 16) * 512
                                          + (((kb * 4 + quad) ^ l15) * 16));
            #pragma unroll
            for (int jn = 0; jn < 2; ++jn)
                #pragma unroll
                for (int im = 0; im < 2; ++im)
                    acc2[im][jn] = __builtin_amdgcn_mfma_f32_16x16x32_bf16(
                        wr[kb % 3][jn], xf[im], acc2[im][jn], 0, 0, 0);
        }
        __syncthreads();   // A2

        #pragma unroll
        for (int im = 0; im < 2; ++im) {
            const int m = l15 + im * 16;
            #pragma unroll
            for (int jn = 0; jn < 2; ++jn) {
                const int gn = wid * 8 + jn * 4 + quad;
                bf16x4 pk;
                #pragma unroll
                for (int r = 0; r < 4; ++r) pk[r] = (__bf16)acc2[im][jn][r];
                *(bf16x4*)((char*)Es + m * 512 + ((gn ^ (l15 << 2)) * 8)) = pk;
            }
        }
        __syncthreads();   // E2

        // ---- store-phase 2: y = x + proj + b (f32) ----
        #pragma unroll
        for (int r = 0; r < 2; ++r) {
            const int m = r * 16 + hrow;
            bf16x8 ev = *(const bf16x8*)((const char*)Es + m * 512 + (((nc * 2) ^ (hrow << 2)) * 8));
            const size_t gidx = (mt0 + m) * 256 + nc * 8;
            f32x4 x0 = *(const f32x4*)&xres[gidx];
            f32x4 x1 = *(const f32x4*)&xres[gidx + 4];
            f32x4 b0 = *(const f32x4*)&bias[nc * 8];
            f32x4 b1 = *(const f32x4*)&bias[nc * 8 + 4];
            f32x4 y0, y1;
            #pragma unroll
            for (int jj = 0; jj < 4; ++jj) {
                y0[jj] = x0[jj] + (float)ev[jj]     + b0[jj];
                y1[jj] = x1[jj] + (float)ev[jj + 4] + b1[jj];
            }
            *(f32x4*)&y[gidx]     = y0;
            *(f32x4*)&y[gidx + 4] = y1;
        }
    }
}

// ---------------- scan pass 2: prefix over chunk carries ----------------
__global__ __launch_bounds__(256) void scan_prefix(float* carry, const float* __restrict__ cL,
                            float* __restrict__ fs_out) {
    int b = blockIdx.x, s = threadIdx.x;
    float cl = cL[s];
    float P = 0.f;
    #pragma unroll
    for (int jo = 0; jo < 8; ++jo) {
        float v[8];
        #pragma unroll
        for (int r = 0; r < 8; ++r)
            v[r] = carry[((size_t)b * NCHUNK + jo * 8 + r) * SS + s];
        float w[8];
        #pragma unroll
        for (int r = 0; r < 8; ++r) { P = cl * P + v[r]; w[r] = P; }
        #pragma unroll
        for (int r = 0; r < 8; ++r)
            carry[((size_t)b * NCHUNK + jo * 8 + r) * SS + s] = w[r];
    }
    fs_out[b * SS + s] = P;
}

extern "C" void kernel_launch(void* const* d_in, const int* in_sizes, int n_in,
                              void* d_out, int out_size, void* d_ws, size_t ws_size,
                              hipStream_t stream) {
    const float* x      = (const float*)d_in[0];
    const float* state0 = (const float*)d_in[1];
    const float* w1     = (const float*)d_in[2];   // in_to_state [S,H]
    const float* w2     = (const float*)d_in[3];   // state_to_hidden [H,S]
    const float* direct = (const float*)d_in[4];
    const float* a_diag = (const float*)d_in[5];
    const float* g_diag = (const float*)d_in[6];
    const float* dt     = (const float*)d_in[7];
    const float* norm_w = (const float*)d_in[8];
    const float* norm_b = (const float*)d_in[9];
    const float* w3     = (const float*)d_in[10];  // out_w [H,H]
    const float* out_b  = (const float*)d_in[11];

    char* ws = (char*)d_ws;
    const size_t MH2 = (size_t)MTOT * HH * 2;      // 67108864
    __bf16* xn    = (__bf16*)(ws);                  // [M,H] bf16
    __bf16* u     = (__bf16*)(ws + MH2);            // [M,S] bf16
    __bf16* w1b   = (__bf16*)(ws + 2*MH2);
    __bf16* w2b   = (__bf16*)(ws + 2*MH2 + 131072);
    __bf16* w3b   = (__bf16*)(ws + 2*MH2 + 262144);
    float*  coeff = (float*)(ws + 2*MH2 + 393216);
    float*  cL    = (float*)(ws + 2*MH2 + 394240);
    float*  carry = (float*)(ws + 2*MH2 + 395264);  // [B, NCHUNK, S] f32 = 2MB

    float* y_out  = (float*)d_out;
    float* fs_out = (float*)d_out + (size_t)MTOT * HH;

    prep_kernel<<<256, 256, 0, stream>>>(w1, w2, w3, w1b, w2b, w3b,
                                         a_diag, g_diag, dt, coeff, cL);
    gemm_ln_kernel<<<512, 512, 0, stream>>>(w1b, x, norm_w, norm_b, xn, u,
                                            coeff, state0, carry);
    scan_prefix<<<BB, 256, 0, stream>>>(carry, cL, fs_out);
    gemm_fused_kernel<<<512, 512, 0, stream>>>(w2b, w3b, u, xn, direct, x, out_b,
                                               coeff, state0, carry, y_out);
}